// Round 1
// baseline (628.244 us; speedup 1.0000x reference)
//
#include <hip/hip_runtime.h>

#define NBINS 4096
#define CAP 4096
#define BATCH 8
#define MASK_TH 0.01f
#define QQ 0.9f

__device__ __forceinline__ int bin_of(float t) {
    int b = (int)(t * (float)NBINS);
    return b > NBINS - 1 ? NBINS - 1 : (b < 0 ? 0 : b);
}

// Pass 1: per-batch histogram of valid target values.
__global__ void k_hist(const float* __restrict__ tgt, int* __restrict__ hist, int nper) {
    __shared__ int lh[NBINS];
    const int b = blockIdx.y;
    for (int i = threadIdx.x; i < NBINS; i += blockDim.x) lh[i] = 0;
    __syncthreads();
    const float4* t4 = (const float4*)(tgt + (size_t)b * nper);
    const int n4 = nper >> 2;
    const int stride = gridDim.x * blockDim.x;
    for (int i = blockIdx.x * blockDim.x + threadIdx.x; i < n4; i += stride) {
        float4 v = t4[i];
        float c[4] = {v.x, v.y, v.z, v.w};
        #pragma unroll
        for (int j = 0; j < 4; ++j)
            if (c[j] > MASK_TH) atomicAdd(&lh[bin_of(c[j])], 1);
    }
    __syncthreads();
    for (int i = threadIdx.x; i < NBINS; i += blockDim.x) {
        int c = lh[i];
        if (c) atomicAdd(&hist[b * NBINS + i], c);
    }
}

// Pass 2: per batch, find bins holding order statistics k_lo, k_hi.
// sel_i[b*4+{0,1,2,3}] = b_lo, b_hi, klo_rel, khi_rel ; sel_f[b*2+0] = frac
__global__ void k_scan(const int* __restrict__ hist, int* __restrict__ sel_i,
                       float* __restrict__ sel_f, int nper) {
    int b = threadIdx.x;
    if (b >= BATCH) return;
    const int* h = hist + b * NBINS;
    int nv = 0;
    for (int i = 0; i < NBINS; ++i) nv += h[i];
    if (nv <= 0) {
        sel_i[b * 4 + 0] = -1;
        sel_f[b * 2 + 0] = 0.f;
        sel_f[b * 2 + 1] = MASK_TH;  // fallback thresh
        return;
    }
    // replicate reference f32 arithmetic exactly
    float pos = (float)(nper - nv) + QQ * (float)(nv - 1);
    float fl = floorf(pos);
    int lo = (int)fl;
    int hi = (int)ceilf(pos);
    lo = lo < 0 ? 0 : (lo > nper - 1 ? nper - 1 : lo);
    hi = hi < 0 ? 0 : (hi > nper - 1 ? nper - 1 : hi);
    float frac = pos - fl;
    int klo = lo - (nper - nv);
    int khi = hi - (nper - nv);
    if (klo < 0) klo = 0;
    if (khi < 0) khi = 0;
    if (klo > nv - 1) klo = nv - 1;
    if (khi > nv - 1) khi = nv - 1;

    int cum = 0, b_lo = -1, b_hi = -1, base = 0;
    for (int i = 0; i < NBINS; ++i) {
        int c = h[i];
        int cumNext = cum + c;
        if (b_lo < 0 && klo < cumNext) { b_lo = i; base = cum; }
        if (b_hi < 0 && khi < cumNext) { b_hi = i; }
        if (b_lo >= 0 && b_hi >= 0) break;
        cum = cumNext;
    }
    sel_i[b * 4 + 0] = b_lo;
    sel_i[b * 4 + 1] = b_hi;
    sel_i[b * 4 + 2] = klo - base;
    sel_i[b * 4 + 3] = khi - base;
    sel_f[b * 2 + 0] = frac;
}

// Pass 3: collect all valid target values whose bin is in [b_lo, b_hi].
__global__ void k_collect(const float* __restrict__ tgt, const int* __restrict__ sel_i,
                          int* __restrict__ cnt, float* __restrict__ buf, int nper) {
    const int b = blockIdx.y;
    const int b_lo = sel_i[b * 4 + 0];
    if (b_lo < 0) return;
    const int b_hi = sel_i[b * 4 + 1];
    const float4* t4 = (const float4*)(tgt + (size_t)b * nper);
    const int n4 = nper >> 2;
    const int stride = gridDim.x * blockDim.x;
    for (int i = blockIdx.x * blockDim.x + threadIdx.x; i < n4; i += stride) {
        float4 v = t4[i];
        float c[4] = {v.x, v.y, v.z, v.w};
        #pragma unroll
        for (int j = 0; j < 4; ++j) {
            float t = c[j];
            if (t > MASK_TH) {
                int bn = bin_of(t);
                if (bn >= b_lo && bn <= b_hi) {
                    int k = atomicAdd(&cnt[b], 1);
                    if (k < CAP) buf[(size_t)b * CAP + k] = t;
                }
            }
        }
    }
}

// Pass 4: exact rank selection among collected values; write thresh.
__global__ void k_select(const int* __restrict__ sel_i, const int* __restrict__ cnt,
                         const float* __restrict__ buf, float* __restrict__ sel_f) {
    __shared__ float v[CAP];
    __shared__ float vlo, vhi;
    const int b = blockIdx.x;
    const int b_lo = sel_i[b * 4 + 0];
    if (b_lo < 0) return;  // thresh already set by k_scan fallback
    int n = cnt[b];
    if (n > CAP) n = CAP;
    for (int i = threadIdx.x; i < n; i += blockDim.x) v[i] = buf[(size_t)b * CAP + i];
    if (threadIdx.x == 0) { vlo = 0.f; vhi = 0.f; }
    __syncthreads();
    const int klo = sel_i[b * 4 + 2];
    const int khi = sel_i[b * 4 + 3];
    for (int i = threadIdx.x; i < n; i += blockDim.x) {
        float x = v[i];
        int r = 0;
        for (int j = 0; j < n; ++j) {
            float y = v[j];
            r += (y < x) || (y == x && j < i);
        }
        if (r == klo) vlo = x;
        if (r == khi) vhi = x;
    }
    __syncthreads();
    if (threadIdx.x == 0) {
        float frac = sel_f[b * 2 + 0];
        sel_f[b * 2 + 1] = vlo + frac * (vhi - vlo);
    }
}

// Pass 5: hot/bg squared-error sums and counts per batch.
__global__ void k_loss(const float* __restrict__ pred, const float* __restrict__ tgt,
                       const float* __restrict__ sel_f, float* __restrict__ acc, int nper) {
    const int b = blockIdx.y;
    const float thresh = sel_f[b * 2 + 1];
    const float4* t4 = (const float4*)(tgt + (size_t)b * nper);
    const float4* p4 = (const float4*)(pred + (size_t)b * nper);
    const int n4 = nper >> 2;
    const int stride = gridDim.x * blockDim.x;
    float hs = 0.f, bs = 0.f, hc = 0.f, bc = 0.f;
    for (int i = blockIdx.x * blockDim.x + threadIdx.x; i < n4; i += stride) {
        float4 tv = t4[i];
        float4 pv = p4[i];
        float tc[4] = {tv.x, tv.y, tv.z, tv.w};
        float pc[4] = {pv.x, pv.y, pv.z, pv.w};
        #pragma unroll
        for (int j = 0; j < 4; ++j) {
            float t = tc[j];
            if (t > MASK_TH) {
                float e = pc[j] - t;
                float e2 = e * e;
                if (t > thresh) { hs += e2; hc += 1.f; }
                else            { bs += e2; bc += 1.f; }
            }
        }
    }
    #pragma unroll
    for (int off = 32; off > 0; off >>= 1) {
        hs += __shfl_down(hs, off);
        bs += __shfl_down(bs, off);
        hc += __shfl_down(hc, off);
        bc += __shfl_down(bc, off);
    }
    __shared__ float sh[4][4];
    const int wid = threadIdx.x >> 6;
    const int lane = threadIdx.x & 63;
    if (lane == 0) { sh[wid][0] = hs; sh[wid][1] = bs; sh[wid][2] = hc; sh[wid][3] = bc; }
    __syncthreads();
    if (threadIdx.x == 0) {
        float a0 = 0, a1 = 0, a2 = 0, a3 = 0;
        const int nw = blockDim.x >> 6;
        for (int w = 0; w < nw; ++w) { a0 += sh[w][0]; a1 += sh[w][1]; a2 += sh[w][2]; a3 += sh[w][3]; }
        atomicAdd(&acc[b * 4 + 0], a0);
        atomicAdd(&acc[b * 4 + 1], a1);
        atomicAdd(&acc[b * 4 + 2], a2);
        atomicAdd(&acc[b * 4 + 3], a3);
    }
}

// Pass 6: combine.
__global__ void k_final(const float* __restrict__ acc, float* __restrict__ out) {
    if (threadIdx.x == 0 && blockIdx.x == 0) {
        float s = 0.f;
        for (int b = 0; b < BATCH; ++b) {
            float hl = acc[b * 4 + 0] / (acc[b * 4 + 2] + 1e-8f);
            float bl = acc[b * 4 + 1] / (acc[b * 4 + 3] + 1e-8f);
            s += 5.0f * hl + bl;
        }
        out[0] = s / (float)BATCH;
    }
}

extern "C" void kernel_launch(void* const* d_in, const int* in_sizes, int n_in,
                              void* d_out, int out_size, void* d_ws, size_t ws_size,
                              hipStream_t stream) {
    const float* pred = (const float*)d_in[0];
    const float* tgt  = (const float*)d_in[1];
    float* out = (float*)d_out;
    const int total = in_sizes[0];
    const int nper = total / BATCH;

    int*   hist  = (int*)d_ws;                      // B*NBINS ints
    int*   cnt   = hist + BATCH * NBINS;            // B ints
    int*   sel_i = cnt + BATCH;                     // B*4 ints
    float* sel_f = (float*)(sel_i + BATCH * 4);     // B*2 floats
    float* acc   = sel_f + BATCH * 2;               // B*4 floats
    float* buf   = acc + BATCH * 4;                 // B*CAP floats

    const size_t zero_bytes = (size_t)((char*)buf - (char*)d_ws);
    hipMemsetAsync(d_ws, 0, zero_bytes, stream);

    k_hist   <<<dim3(64, BATCH), 256, 0, stream>>>(tgt, hist, nper);
    k_scan   <<<1, 64, 0, stream>>>(hist, sel_i, sel_f, nper);
    k_collect<<<dim3(64, BATCH), 256, 0, stream>>>(tgt, sel_i, cnt, buf, nper);
    k_select <<<BATCH, 256, 0, stream>>>(sel_i, cnt, buf, sel_f);
    k_loss   <<<dim3(128, BATCH), 256, 0, stream>>>(pred, tgt, sel_f, acc, nper);
    k_final  <<<1, 1, 0, stream>>>(acc, out);
}

// Round 2
// 184.415 us; speedup vs baseline: 3.4067x; 3.4067x over previous
//
#include <hip/hip_runtime.h>

#define NBINS 4096
#define CAP 4096
#define BATCH 8
#define MASK_TH 0.01f
#define QQ 0.9f
#define SCAN_T 256
#define CHUNK (NBINS / SCAN_T)   // 16 bins per thread

__device__ __forceinline__ int bin_of(float t) {
    int b = (int)(t * (float)NBINS);
    return b > NBINS - 1 ? NBINS - 1 : (b < 0 ? 0 : b);
}

// Pass 1: per-batch histogram of valid target values.
__global__ void k_hist(const float* __restrict__ tgt, int* __restrict__ hist, int nper) {
    __shared__ int lh[NBINS];
    const int b = blockIdx.y;
    for (int i = threadIdx.x; i < NBINS; i += blockDim.x) lh[i] = 0;
    __syncthreads();
    const float4* t4 = (const float4*)(tgt + (size_t)b * nper);
    const int n4 = nper >> 2;
    const int stride = gridDim.x * blockDim.x;
    for (int i = blockIdx.x * blockDim.x + threadIdx.x; i < n4; i += stride) {
        float4 v = t4[i];
        float c[4] = {v.x, v.y, v.z, v.w};
        #pragma unroll
        for (int j = 0; j < 4; ++j)
            if (c[j] > MASK_TH) atomicAdd(&lh[bin_of(c[j])], 1);
    }
    __syncthreads();
    for (int i = threadIdx.x; i < NBINS; i += blockDim.x) {
        int c = lh[i];
        if (c) atomicAdd(&hist[b * NBINS + i], c);
    }
}

// Pass 2 (parallel): per batch, find bins holding order statistics k_lo, k_hi.
// One block per batch. LDS-staged histogram + block scan.
// sel_i[b*4+{0,1,2,3}] = b_lo, b_hi, klo_rel, khi_rel ; sel_f[b*2+0] = frac
__global__ void k_scan(const int* __restrict__ hist, int* __restrict__ sel_i,
                       float* __restrict__ sel_f, int nper) {
    const int b = blockIdx.x;
    const int tid = threadIdx.x;  // SCAN_T threads
    __shared__ int lh[NBINS];
    __shared__ int csum[SCAN_T];
    __shared__ int s_blo, s_bhi, s_base_lo;
    const int* h = hist + b * NBINS;
    for (int i = tid; i < NBINS; i += SCAN_T) lh[i] = h[i];
    __syncthreads();
    int mysum = 0;
    #pragma unroll
    for (int j = 0; j < CHUNK; ++j) mysum += lh[tid * CHUNK + j];
    csum[tid] = mysum;
    __syncthreads();
    // inclusive Hillis-Steele scan over csum
    for (int off = 1; off < SCAN_T; off <<= 1) {
        int v = (tid >= off) ? csum[tid - off] : 0;
        __syncthreads();
        csum[tid] += v;
        __syncthreads();
    }
    const int nv = csum[SCAN_T - 1];
    if (nv <= 0) {
        if (tid == 0) {
            sel_i[b * 4 + 0] = -1;
            sel_f[b * 2 + 0] = 0.f;
            sel_f[b * 2 + 1] = MASK_TH;  // fallback thresh
        }
        return;
    }
    // replicate reference f32 arithmetic exactly (all threads compute same)
    float pos = (float)(nper - nv) + QQ * (float)(nv - 1);
    float fl = floorf(pos);
    int lo = (int)fl;
    int hi = (int)ceilf(pos);
    lo = lo < 0 ? 0 : (lo > nper - 1 ? nper - 1 : lo);
    hi = hi < 0 ? 0 : (hi > nper - 1 ? nper - 1 : hi);
    float frac = pos - fl;
    int klo = lo - (nper - nv);
    int khi = hi - (nper - nv);
    if (klo < 0) klo = 0;
    if (khi < 0) khi = 0;
    if (klo > nv - 1) klo = nv - 1;
    if (khi > nv - 1) khi = nv - 1;

    int cum = csum[tid] - mysum;  // exclusive prefix of this thread's chunk
    #pragma unroll
    for (int j = 0; j < CHUNK; ++j) {
        int c = lh[tid * CHUNK + j];
        if (c > 0) {
            if (klo >= cum && klo < cum + c) { s_blo = tid * CHUNK + j; s_base_lo = cum; }
            if (khi >= cum && khi < cum + c) { s_bhi = tid * CHUNK + j; }
        }
        cum += c;
    }
    __syncthreads();
    if (tid == 0) {
        sel_i[b * 4 + 0] = s_blo;
        sel_i[b * 4 + 1] = s_bhi;
        sel_i[b * 4 + 2] = klo - s_base_lo;
        sel_i[b * 4 + 3] = khi - s_base_lo;
        sel_f[b * 2 + 0] = frac;
    }
}

// Pass 3: collect all valid target values whose bin is in [b_lo, b_hi].
__global__ void k_collect(const float* __restrict__ tgt, const int* __restrict__ sel_i,
                          int* __restrict__ cnt, float* __restrict__ buf, int nper) {
    const int b = blockIdx.y;
    const int b_lo = sel_i[b * 4 + 0];
    if (b_lo < 0) return;
    const int b_hi = sel_i[b * 4 + 1];
    const float4* t4 = (const float4*)(tgt + (size_t)b * nper);
    const int n4 = nper >> 2;
    const int stride = gridDim.x * blockDim.x;
    for (int i = blockIdx.x * blockDim.x + threadIdx.x; i < n4; i += stride) {
        float4 v = t4[i];
        float c[4] = {v.x, v.y, v.z, v.w};
        #pragma unroll
        for (int j = 0; j < 4; ++j) {
            float t = c[j];
            if (t > MASK_TH) {
                int bn = bin_of(t);
                if (bn >= b_lo && bn <= b_hi) {
                    int k = atomicAdd(&cnt[b], 1);
                    if (k < CAP) buf[(size_t)b * CAP + k] = t;
                }
            }
        }
    }
}

// Pass 4: exact rank selection among collected values; write thresh.
__global__ void k_select(const int* __restrict__ sel_i, const int* __restrict__ cnt,
                         const float* __restrict__ buf, float* __restrict__ sel_f) {
    __shared__ float v[CAP];
    __shared__ float vlo, vhi;
    const int b = blockIdx.x;
    const int b_lo = sel_i[b * 4 + 0];
    if (b_lo < 0) return;  // thresh already set by k_scan fallback
    int n = cnt[b];
    if (n > CAP) n = CAP;
    for (int i = threadIdx.x; i < n; i += blockDim.x) v[i] = buf[(size_t)b * CAP + i];
    if (threadIdx.x == 0) { vlo = 0.f; vhi = 0.f; }
    __syncthreads();
    const int klo = sel_i[b * 4 + 2];
    const int khi = sel_i[b * 4 + 3];
    for (int i = threadIdx.x; i < n; i += blockDim.x) {
        float x = v[i];
        int r = 0;
        for (int j = 0; j < n; ++j) {
            float y = v[j];
            r += (y < x) || (y == x && j < i);
        }
        if (r == klo) vlo = x;
        if (r == khi) vhi = x;
    }
    __syncthreads();
    if (threadIdx.x == 0) {
        float frac = sel_f[b * 2 + 0];
        sel_f[b * 2 + 1] = vlo + frac * (vhi - vlo);
    }
}

// Pass 5: hot/bg squared-error sums and counts per batch.
__global__ void k_loss(const float* __restrict__ pred, const float* __restrict__ tgt,
                       const float* __restrict__ sel_f, float* __restrict__ acc, int nper) {
    const int b = blockIdx.y;
    const float thresh = sel_f[b * 2 + 1];
    const float4* t4 = (const float4*)(tgt + (size_t)b * nper);
    const float4* p4 = (const float4*)(pred + (size_t)b * nper);
    const int n4 = nper >> 2;
    const int stride = gridDim.x * blockDim.x;
    float hs = 0.f, bs = 0.f, hc = 0.f, bc = 0.f;
    for (int i = blockIdx.x * blockDim.x + threadIdx.x; i < n4; i += stride) {
        float4 tv = t4[i];
        float4 pv = p4[i];
        float tc[4] = {tv.x, tv.y, tv.z, tv.w};
        float pc[4] = {pv.x, pv.y, pv.z, pv.w};
        #pragma unroll
        for (int j = 0; j < 4; ++j) {
            float t = tc[j];
            if (t > MASK_TH) {
                float e = pc[j] - t;
                float e2 = e * e;
                if (t > thresh) { hs += e2; hc += 1.f; }
                else            { bs += e2; bc += 1.f; }
            }
        }
    }
    #pragma unroll
    for (int off = 32; off > 0; off >>= 1) {
        hs += __shfl_down(hs, off);
        bs += __shfl_down(bs, off);
        hc += __shfl_down(hc, off);
        bc += __shfl_down(bc, off);
    }
    __shared__ float sh[4][4];
    const int wid = threadIdx.x >> 6;
    const int lane = threadIdx.x & 63;
    if (lane == 0) { sh[wid][0] = hs; sh[wid][1] = bs; sh[wid][2] = hc; sh[wid][3] = bc; }
    __syncthreads();
    if (threadIdx.x == 0) {
        float a0 = 0, a1 = 0, a2 = 0, a3 = 0;
        const int nw = blockDim.x >> 6;
        for (int w = 0; w < nw; ++w) { a0 += sh[w][0]; a1 += sh[w][1]; a2 += sh[w][2]; a3 += sh[w][3]; }
        atomicAdd(&acc[b * 4 + 0], a0);
        atomicAdd(&acc[b * 4 + 1], a1);
        atomicAdd(&acc[b * 4 + 2], a2);
        atomicAdd(&acc[b * 4 + 3], a3);
    }
}

// Pass 6: combine.
__global__ void k_final(const float* __restrict__ acc, float* __restrict__ out) {
    if (threadIdx.x == 0 && blockIdx.x == 0) {
        float s = 0.f;
        for (int b = 0; b < BATCH; ++b) {
            float hl = acc[b * 4 + 0] / (acc[b * 4 + 2] + 1e-8f);
            float bl = acc[b * 4 + 1] / (acc[b * 4 + 3] + 1e-8f);
            s += 5.0f * hl + bl;
        }
        out[0] = s / (float)BATCH;
    }
}

extern "C" void kernel_launch(void* const* d_in, const int* in_sizes, int n_in,
                              void* d_out, int out_size, void* d_ws, size_t ws_size,
                              hipStream_t stream) {
    const float* pred = (const float*)d_in[0];
    const float* tgt  = (const float*)d_in[1];
    float* out = (float*)d_out;
    const int total = in_sizes[0];
    const int nper = total / BATCH;

    int*   hist  = (int*)d_ws;                      // B*NBINS ints
    int*   cnt   = hist + BATCH * NBINS;            // B ints
    int*   sel_i = cnt + BATCH;                     // B*4 ints
    float* sel_f = (float*)(sel_i + BATCH * 4);     // B*2 floats
    float* acc   = sel_f + BATCH * 2;               // B*4 floats
    float* buf   = acc + BATCH * 4;                 // B*CAP floats

    const size_t zero_bytes = (size_t)((char*)buf - (char*)d_ws);
    hipMemsetAsync(d_ws, 0, zero_bytes, stream);

    k_hist   <<<dim3(64, BATCH), 256, 0, stream>>>(tgt, hist, nper);
    k_scan   <<<BATCH, SCAN_T, 0, stream>>>(hist, sel_i, sel_f, nper);
    k_collect<<<dim3(64, BATCH), 256, 0, stream>>>(tgt, sel_i, cnt, buf, nper);
    k_select <<<BATCH, 256, 0, stream>>>(sel_i, cnt, buf, sel_f);
    k_loss   <<<dim3(128, BATCH), 256, 0, stream>>>(pred, tgt, sel_f, acc, nper);
    k_final  <<<1, 1, 0, stream>>>(acc, out);
}

// Round 3
// 173.674 us; speedup vs baseline: 3.6174x; 1.0619x over previous
//
#include <hip/hip_runtime.h>

#define NBINS 4096
#define CAP 4096
#define BATCH 8
#define MASK_TH 0.01f
#define QQ 0.9f
#define SCAN_T 256
#define CHUNK (NBINS / SCAN_T)   // 16 bins per thread
#define EPSF 1e-8f

__device__ __forceinline__ int bin_of(float t) {
    int b = (int)(t * (float)NBINS);
    return b > NBINS - 1 ? NBINS - 1 : (b < 0 ? 0 : b);
}

// Pass 1: per-batch histogram of valid target values.
__global__ void k_hist(const float* __restrict__ tgt, int* __restrict__ hist, int nper) {
    __shared__ int lh[NBINS];
    const int b = blockIdx.y;
    for (int i = threadIdx.x; i < NBINS; i += blockDim.x) lh[i] = 0;
    __syncthreads();
    const float4* t4 = (const float4*)(tgt + (size_t)b * nper);
    const int n4 = nper >> 2;
    const int stride = gridDim.x * blockDim.x;
    const int base = blockIdx.x * blockDim.x + threadIdx.x;
    for (int i = base; i < n4; i += 2 * stride) {
        float4 v0 = t4[i];
        bool has1 = (i + stride) < n4;
        float4 v1 = has1 ? t4[i + stride] : make_float4(0.f, 0.f, 0.f, 0.f);
        float c0[4] = {v0.x, v0.y, v0.z, v0.w};
        #pragma unroll
        for (int j = 0; j < 4; ++j)
            if (c0[j] > MASK_TH) atomicAdd(&lh[bin_of(c0[j])], 1);
        if (has1) {
            float c1[4] = {v1.x, v1.y, v1.z, v1.w};
            #pragma unroll
            for (int j = 0; j < 4; ++j)
                if (c1[j] > MASK_TH) atomicAdd(&lh[bin_of(c1[j])], 1);
        }
    }
    __syncthreads();
    for (int i = threadIdx.x; i < NBINS; i += blockDim.x) {
        int c = lh[i];
        if (c) atomicAdd(&hist[b * NBINS + i], c);
    }
}

// Pass 2: per batch, find bins holding order statistics k_lo, k_hi.
// sel_i[b*4+{0,1,2,3}] = b_lo, b_hi, klo_rel, khi_rel ; sel_f[b*2+0] = frac
__global__ void k_scan(const int* __restrict__ hist, int* __restrict__ sel_i,
                       float* __restrict__ sel_f, int nper) {
    const int b = blockIdx.x;
    const int tid = threadIdx.x;
    __shared__ int lh[NBINS];
    __shared__ int csum[SCAN_T];
    __shared__ int s_blo, s_bhi, s_base_lo;
    const int* h = hist + b * NBINS;
    for (int i = tid; i < NBINS; i += SCAN_T) lh[i] = h[i];
    __syncthreads();
    int mysum = 0;
    #pragma unroll
    for (int j = 0; j < CHUNK; ++j) mysum += lh[tid * CHUNK + j];
    csum[tid] = mysum;
    __syncthreads();
    for (int off = 1; off < SCAN_T; off <<= 1) {
        int v = (tid >= off) ? csum[tid - off] : 0;
        __syncthreads();
        csum[tid] += v;
        __syncthreads();
    }
    const int nv = csum[SCAN_T - 1];
    if (nv <= 0) {
        if (tid == 0) {
            sel_i[b * 4 + 0] = -1;
            sel_i[b * 4 + 1] = -1;
            sel_i[b * 4 + 2] = 0;
            sel_i[b * 4 + 3] = 0;
            sel_f[b * 2 + 0] = 0.f;
        }
        return;
    }
    float pos = (float)(nper - nv) + QQ * (float)(nv - 1);
    float fl = floorf(pos);
    int lo = (int)fl;
    int hi = (int)ceilf(pos);
    lo = lo < 0 ? 0 : (lo > nper - 1 ? nper - 1 : lo);
    hi = hi < 0 ? 0 : (hi > nper - 1 ? nper - 1 : hi);
    float frac = pos - fl;
    int klo = lo - (nper - nv);
    int khi = hi - (nper - nv);
    if (klo < 0) klo = 0;
    if (khi < 0) khi = 0;
    if (klo > nv - 1) klo = nv - 1;
    if (khi > nv - 1) khi = nv - 1;

    int cum = csum[tid] - mysum;
    #pragma unroll
    for (int j = 0; j < CHUNK; ++j) {
        int c = lh[tid * CHUNK + j];
        if (c > 0) {
            if (klo >= cum && klo < cum + c) { s_blo = tid * CHUNK + j; s_base_lo = cum; }
            if (khi >= cum && khi < cum + c) { s_bhi = tid * CHUNK + j; }
        }
        cum += c;
    }
    __syncthreads();
    if (tid == 0) {
        sel_i[b * 4 + 0] = s_blo;
        sel_i[b * 4 + 1] = s_bhi;
        sel_i[b * 4 + 2] = klo - s_base_lo;
        sel_i[b * 4 + 3] = khi - s_base_lo;
        sel_f[b * 2 + 0] = frac;
    }
}

// Pass 3 (fused): definite hot/bg e2 sums + counts; collect ambiguous (t,e2).
// acc[b*4+{0,1,2,3}] = hot_e2, bg_e2, hot_cnt, bg_cnt  (definite only)
__global__ void k_fused(const float* __restrict__ pred, const float* __restrict__ tgt,
                        const int* __restrict__ sel_i, int* __restrict__ cnt,
                        float* __restrict__ buf_t, float* __restrict__ buf_e,
                        float* __restrict__ acc, int nper) {
    const int b = blockIdx.y;
    const int b_lo = sel_i[b * 4 + 0];
    const int b_hi = sel_i[b * 4 + 1];
    const float4* t4 = (const float4*)(tgt + (size_t)b * nper);
    const float4* p4 = (const float4*)(pred + (size_t)b * nper);
    const int n4 = nper >> 2;
    const int stride = gridDim.x * blockDim.x;
    const int base = blockIdx.x * blockDim.x + threadIdx.x;
    float hs = 0.f, bs = 0.f, hc = 0.f, bc = 0.f;
    for (int i = base; i < n4; i += 2 * stride) {
        float4 tv0 = t4[i];
        float4 pv0 = p4[i];
        bool has1 = (i + stride) < n4;
        float4 tv1 = has1 ? t4[i + stride] : make_float4(0.f, 0.f, 0.f, 0.f);
        float4 pv1 = has1 ? p4[i + stride] : make_float4(0.f, 0.f, 0.f, 0.f);
        float tc[8] = {tv0.x, tv0.y, tv0.z, tv0.w, tv1.x, tv1.y, tv1.z, tv1.w};
        float pc[8] = {pv0.x, pv0.y, pv0.z, pv0.w, pv1.x, pv1.y, pv1.z, pv1.w};
        #pragma unroll
        for (int j = 0; j < 8; ++j) {
            float t = tc[j];
            bool valid = t > MASK_TH;
            if (!valid) continue;
            float e = pc[j] - t;
            float e2 = e * e;
            int bn = bin_of(t);
            if (bn > b_hi)      { hs += e2; hc += 1.f; }
            else if (bn < b_lo) { bs += e2; bc += 1.f; }
            else {
                int k = atomicAdd(&cnt[b], 1);
                if (k < CAP) {
                    buf_t[(size_t)b * CAP + k] = t;
                    buf_e[(size_t)b * CAP + k] = e2;
                }
            }
        }
    }
    #pragma unroll
    for (int off = 32; off > 0; off >>= 1) {
        hs += __shfl_down(hs, off);
        bs += __shfl_down(bs, off);
        hc += __shfl_down(hc, off);
        bc += __shfl_down(bc, off);
    }
    __shared__ float sh[4][4];
    const int wid = threadIdx.x >> 6;
    const int lane = threadIdx.x & 63;
    if (lane == 0) { sh[wid][0] = hs; sh[wid][1] = bs; sh[wid][2] = hc; sh[wid][3] = bc; }
    __syncthreads();
    if (threadIdx.x == 0) {
        float a0 = 0, a1 = 0, a2 = 0, a3 = 0;
        const int nw = blockDim.x >> 6;
        for (int w = 0; w < nw; ++w) { a0 += sh[w][0]; a1 += sh[w][1]; a2 += sh[w][2]; a3 += sh[w][3]; }
        atomicAdd(&acc[b * 4 + 0], a0);
        atomicAdd(&acc[b * 4 + 1], a1);
        atomicAdd(&acc[b * 4 + 2], a2);
        atomicAdd(&acc[b * 4 + 3], a3);
    }
}

// Pass 4: per batch — exact rank select among candidates, classify them,
// combine with definite sums -> per-batch combined loss.
__global__ void k_finish(const int* __restrict__ sel_i, const float* __restrict__ sel_f,
                         const int* __restrict__ cnt, const float* __restrict__ buf_t,
                         const float* __restrict__ buf_e, const float* __restrict__ acc,
                         float* __restrict__ acc2) {
    __shared__ float st[CAP];
    __shared__ float vlo, vhi;
    __shared__ float red[4][4];
    const int b = blockIdx.x;
    const int b_lo = sel_i[b * 4 + 0];
    int n = (b_lo < 0) ? 0 : cnt[b];
    if (n > CAP) n = CAP;
    for (int i = threadIdx.x; i < n; i += blockDim.x) st[i] = buf_t[(size_t)b * CAP + i];
    if (threadIdx.x == 0) { vlo = 0.f; vhi = 0.f; }
    __syncthreads();
    const int klo = sel_i[b * 4 + 2];
    const int khi = sel_i[b * 4 + 3];
    for (int i = threadIdx.x; i < n; i += blockDim.x) {
        float x = st[i];
        int r = 0;
        for (int j = 0; j < n; ++j) {
            float y = st[j];
            r += (y < x) || (y == x && j < i);
        }
        if (r == klo) vlo = x;
        if (r == khi) vhi = x;
    }
    __syncthreads();
    const float frac = sel_f[b * 2 + 0];
    const float thresh = vlo + frac * (vhi - vlo);
    // classify candidates
    float hs = 0.f, bs = 0.f, hc = 0.f, bc = 0.f;
    for (int i = threadIdx.x; i < n; i += blockDim.x) {
        float t = st[i];
        float e2 = buf_e[(size_t)b * CAP + i];
        if (t > thresh) { hs += e2; hc += 1.f; }
        else            { bs += e2; bc += 1.f; }
    }
    #pragma unroll
    for (int off = 32; off > 0; off >>= 1) {
        hs += __shfl_down(hs, off);
        bs += __shfl_down(bs, off);
        hc += __shfl_down(hc, off);
        bc += __shfl_down(bc, off);
    }
    const int wid = threadIdx.x >> 6;
    const int lane = threadIdx.x & 63;
    if (lane == 0) { red[wid][0] = hs; red[wid][1] = bs; red[wid][2] = hc; red[wid][3] = bc; }
    __syncthreads();
    if (threadIdx.x == 0) {
        float a0 = 0, a1 = 0, a2 = 0, a3 = 0;
        const int nw = blockDim.x >> 6;
        for (int w = 0; w < nw; ++w) { a0 += red[w][0]; a1 += red[w][1]; a2 += red[w][2]; a3 += red[w][3]; }
        float th = acc[b * 4 + 0] + a0;
        float tb = acc[b * 4 + 1] + a1;
        float nh = acc[b * 4 + 2] + a2;
        float nb = acc[b * 4 + 3] + a3;
        float hl = th / (nh + EPSF);
        float bl = tb / (nb + EPSF);
        acc2[b] = 5.0f * hl + bl;
    }
}

// Pass 5: mean over batches.
__global__ void k_final(const float* __restrict__ acc2, float* __restrict__ out) {
    if (threadIdx.x == 0 && blockIdx.x == 0) {
        float s = 0.f;
        for (int b = 0; b < BATCH; ++b) s += acc2[b];
        out[0] = s / (float)BATCH;
    }
}

extern "C" void kernel_launch(void* const* d_in, const int* in_sizes, int n_in,
                              void* d_out, int out_size, void* d_ws, size_t ws_size,
                              hipStream_t stream) {
    const float* pred = (const float*)d_in[0];
    const float* tgt  = (const float*)d_in[1];
    float* out = (float*)d_out;
    const int total = in_sizes[0];
    const int nper = total / BATCH;

    int*   hist  = (int*)d_ws;                      // B*NBINS ints
    int*   cnt   = hist + BATCH * NBINS;            // B ints
    int*   sel_i = cnt + BATCH;                     // B*4 ints
    float* sel_f = (float*)(sel_i + BATCH * 4);     // B*2 floats
    float* acc   = sel_f + BATCH * 2;               // B*4 floats
    float* acc2  = acc + BATCH * 4;                 // B floats
    float* buf_t = acc2 + BATCH;                    // B*CAP floats
    float* buf_e = buf_t + BATCH * CAP;             // B*CAP floats

    const size_t zero_bytes = (size_t)((char*)buf_t - (char*)d_ws);
    hipMemsetAsync(d_ws, 0, zero_bytes, stream);

    k_hist  <<<dim3(128, BATCH), 256, 0, stream>>>(tgt, hist, nper);
    k_scan  <<<BATCH, SCAN_T, 0, stream>>>(hist, sel_i, sel_f, nper);
    k_fused <<<dim3(256, BATCH), 256, 0, stream>>>(pred, tgt, sel_i, cnt, buf_t, buf_e, acc, nper);
    k_finish<<<BATCH, 256, 0, stream>>>(sel_i, sel_f, cnt, buf_t, buf_e, acc, acc2);
    k_final <<<1, 1, 0, stream>>>(acc2, out);
}

// Round 4
// 127.246 us; speedup vs baseline: 4.9372x; 1.3649x over previous
//
#include <hip/hip_runtime.h>

#define NBINS 4096
#define CAP 4096
#define BATCH 8
#define MASK_TH 0.01f
#define QQ 0.9f
#define SCAN_T 256
#define CHUNK (NBINS / SCAN_T)   // 16 bins per thread
#define EPSF 1e-8f

__device__ __forceinline__ int bin_of(float t) {
    int b = (int)(t * (float)NBINS);
    return b > NBINS - 1 ? NBINS - 1 : (b < 0 ? 0 : b);
}

// Pass 1: per-batch histogram of valid target values. Branch-free inner loop:
// invalid values hit dummy bin NBINS. 4x float4 unrolled unconditional loads.
__global__ void k_hist(const float* __restrict__ tgt, int* __restrict__ hist, int nper) {
    __shared__ int lh[NBINS + 1];
    const int b = blockIdx.y;
    for (int i = threadIdx.x; i < NBINS + 1; i += blockDim.x) lh[i] = 0;
    __syncthreads();
    const float4* t4 = (const float4*)(tgt + (size_t)b * nper);
    const int n4 = nper >> 2;
    const int S = gridDim.x * blockDim.x;
    const int base = blockIdx.x * blockDim.x + threadIdx.x;
    const int quads = n4 / (4 * S);
#define H1(t) atomicAdd(&lh[((t) > MASK_TH) ? bin_of(t) : NBINS], 1)
    for (int q = 0; q < quads; ++q) {
        const int i = base + q * 4 * S;
        float4 v0 = t4[i];
        float4 v1 = t4[i + S];
        float4 v2 = t4[i + 2 * S];
        float4 v3 = t4[i + 3 * S];
        H1(v0.x); H1(v0.y); H1(v0.z); H1(v0.w);
        H1(v1.x); H1(v1.y); H1(v1.z); H1(v1.w);
        H1(v2.x); H1(v2.y); H1(v2.z); H1(v2.w);
        H1(v3.x); H1(v3.y); H1(v3.z); H1(v3.w);
    }
    for (int i = base + quads * 4 * S; i < n4; i += S) {
        float4 v = t4[i];
        H1(v.x); H1(v.y); H1(v.z); H1(v.w);
    }
#undef H1
    __syncthreads();
    for (int i = threadIdx.x; i < NBINS; i += blockDim.x) {
        int c = lh[i];
        if (c) atomicAdd(&hist[b * NBINS + i], c);
    }
}

// Pass 2: per batch, find bins holding order statistics k_lo, k_hi.
// Also zeroes out[0] (batch-0 block) so k_finish can atomicAdd into it.
// sel_i[b*4+{0,1,2,3}] = b_lo, b_hi, klo_rel, khi_rel ; sel_f[b*2+0] = frac
__global__ void k_scan(const int* __restrict__ hist, int* __restrict__ sel_i,
                       float* __restrict__ sel_f, float* __restrict__ out, int nper) {
    const int b = blockIdx.x;
    const int tid = threadIdx.x;
    if (b == 0 && tid == 0) out[0] = 0.f;
    __shared__ int lh[NBINS];
    __shared__ int csum[SCAN_T];
    __shared__ int s_blo, s_bhi, s_base_lo;
    const int* h = hist + b * NBINS;
    for (int i = tid; i < NBINS; i += SCAN_T) lh[i] = h[i];
    __syncthreads();
    int mysum = 0;
    #pragma unroll
    for (int j = 0; j < CHUNK; ++j) mysum += lh[tid * CHUNK + j];
    csum[tid] = mysum;
    __syncthreads();
    for (int off = 1; off < SCAN_T; off <<= 1) {
        int v = (tid >= off) ? csum[tid - off] : 0;
        __syncthreads();
        csum[tid] += v;
        __syncthreads();
    }
    const int nv = csum[SCAN_T - 1];
    if (nv <= 0) {
        if (tid == 0) {
            sel_i[b * 4 + 0] = -1;
            sel_i[b * 4 + 1] = -1;
            sel_i[b * 4 + 2] = 0;
            sel_i[b * 4 + 3] = 0;
            sel_f[b * 2 + 0] = 0.f;
        }
        return;
    }
    float pos = (float)(nper - nv) + QQ * (float)(nv - 1);
    float fl = floorf(pos);
    int lo = (int)fl;
    int hi = (int)ceilf(pos);
    lo = lo < 0 ? 0 : (lo > nper - 1 ? nper - 1 : lo);
    hi = hi < 0 ? 0 : (hi > nper - 1 ? nper - 1 : hi);
    float frac = pos - fl;
    int klo = lo - (nper - nv);
    int khi = hi - (nper - nv);
    if (klo < 0) klo = 0;
    if (khi < 0) khi = 0;
    if (klo > nv - 1) klo = nv - 1;
    if (khi > nv - 1) khi = nv - 1;

    int cum = csum[tid] - mysum;
    #pragma unroll
    for (int j = 0; j < CHUNK; ++j) {
        int c = lh[tid * CHUNK + j];
        if (c > 0) {
            if (klo >= cum && klo < cum + c) { s_blo = tid * CHUNK + j; s_base_lo = cum; }
            if (khi >= cum && khi < cum + c) { s_bhi = tid * CHUNK + j; }
        }
        cum += c;
    }
    __syncthreads();
    if (tid == 0) {
        sel_i[b * 4 + 0] = s_blo;
        sel_i[b * 4 + 1] = s_bhi;
        sel_i[b * 4 + 2] = klo - s_base_lo;
        sel_i[b * 4 + 3] = khi - s_base_lo;
        sel_f[b * 2 + 0] = frac;
    }
}

// Pass 3 (fused): definite hot/bg e2 sums + counts; collect ambiguous (t,e2).
// Main path branch-free; ambiguous path behind one __any per 16 elements.
__global__ void k_fused(const float* __restrict__ pred, const float* __restrict__ tgt,
                        const int* __restrict__ sel_i, int* __restrict__ cnt,
                        float* __restrict__ buf_t, float* __restrict__ buf_e,
                        float* __restrict__ acc, int nper) {
    const int b = blockIdx.y;
    const int b_lo = sel_i[b * 4 + 0];
    const int b_hi = sel_i[b * 4 + 1];
    const float4* t4 = (const float4*)(tgt + (size_t)b * nper);
    const float4* p4 = (const float4*)(pred + (size_t)b * nper);
    const int n4 = nper >> 2;
    const int S = gridDim.x * blockDim.x;
    const int base = blockIdx.x * blockDim.x + threadIdx.x;
    const int quads = n4 / (4 * S);
    float hs = 0.f, bs = 0.f, hc = 0.f, bc = 0.f;

#define E1(j, tt, pp) { \
        float t = (tt); \
        float e = (pp) - t; \
        float e2 = e * e; \
        int bn = bin_of(t); \
        bool valid = t > MASK_TH; \
        bool hot = valid && (bn > b_hi); \
        bool bg  = valid && (bn < b_lo); \
        hs += hot ? e2 : 0.f; hc += hot ? 1.f : 0.f; \
        bs += bg  ? e2 : 0.f; bc += bg  ? 1.f : 0.f; \
        ambBits |= (valid && !(hot || bg)) ? (1 << (j)) : 0; \
    }
#define A1(j, tt, pp) if (ambBits & (1 << (j))) { \
        float t = (tt); \
        float e = (pp) - t; \
        float e2 = e * e; \
        int k = atomicAdd(&cnt[b], 1); \
        if (k < CAP) { buf_t[(size_t)b * CAP + k] = t; buf_e[(size_t)b * CAP + k] = e2; } \
    }

    for (int q = 0; q < quads; ++q) {
        const int i = base + q * 4 * S;
        float4 t0 = t4[i];
        float4 t1 = t4[i + S];
        float4 t2 = t4[i + 2 * S];
        float4 t3 = t4[i + 3 * S];
        float4 p0 = p4[i];
        float4 p1 = p4[i + S];
        float4 p2 = p4[i + 2 * S];
        float4 p3 = p4[i + 3 * S];
        int ambBits = 0;
        E1(0,  t0.x, p0.x); E1(1,  t0.y, p0.y); E1(2,  t0.z, p0.z); E1(3,  t0.w, p0.w);
        E1(4,  t1.x, p1.x); E1(5,  t1.y, p1.y); E1(6,  t1.z, p1.z); E1(7,  t1.w, p1.w);
        E1(8,  t2.x, p2.x); E1(9,  t2.y, p2.y); E1(10, t2.z, p2.z); E1(11, t2.w, p2.w);
        E1(12, t3.x, p3.x); E1(13, t3.y, p3.y); E1(14, t3.z, p3.z); E1(15, t3.w, p3.w);
        if (__any(ambBits != 0)) {
            A1(0,  t0.x, p0.x); A1(1,  t0.y, p0.y); A1(2,  t0.z, p0.z); A1(3,  t0.w, p0.w);
            A1(4,  t1.x, p1.x); A1(5,  t1.y, p1.y); A1(6,  t1.z, p1.z); A1(7,  t1.w, p1.w);
            A1(8,  t2.x, p2.x); A1(9,  t2.y, p2.y); A1(10, t2.z, p2.z); A1(11, t2.w, p2.w);
            A1(12, t3.x, p3.x); A1(13, t3.y, p3.y); A1(14, t3.z, p3.z); A1(15, t3.w, p3.w);
        }
    }
    for (int i = base + quads * 4 * S; i < n4; i += S) {
        float4 t0 = t4[i];
        float4 p0 = p4[i];
        int ambBits = 0;
        E1(0, t0.x, p0.x); E1(1, t0.y, p0.y); E1(2, t0.z, p0.z); E1(3, t0.w, p0.w);
        if (__any(ambBits != 0)) {
            A1(0, t0.x, p0.x); A1(1, t0.y, p0.y); A1(2, t0.z, p0.z); A1(3, t0.w, p0.w);
        }
    }
#undef E1
#undef A1

    #pragma unroll
    for (int off = 32; off > 0; off >>= 1) {
        hs += __shfl_down(hs, off);
        bs += __shfl_down(bs, off);
        hc += __shfl_down(hc, off);
        bc += __shfl_down(bc, off);
    }
    __shared__ float sh[4][4];
    const int wid = threadIdx.x >> 6;
    const int lane = threadIdx.x & 63;
    if (lane == 0) { sh[wid][0] = hs; sh[wid][1] = bs; sh[wid][2] = hc; sh[wid][3] = bc; }
    __syncthreads();
    if (threadIdx.x == 0) {
        float a0 = 0, a1 = 0, a2 = 0, a3 = 0;
        const int nw = blockDim.x >> 6;
        for (int w = 0; w < nw; ++w) { a0 += sh[w][0]; a1 += sh[w][1]; a2 += sh[w][2]; a3 += sh[w][3]; }
        atomicAdd(&acc[b * 4 + 0], a0);
        atomicAdd(&acc[b * 4 + 1], a1);
        atomicAdd(&acc[b * 4 + 2], a2);
        atomicAdd(&acc[b * 4 + 3], a3);
    }
}

// Pass 4: per batch — exact rank select among candidates, classify them,
// combine with definite sums, atomicAdd contribution into out[0].
__global__ void k_finish(const int* __restrict__ sel_i, const float* __restrict__ sel_f,
                         const int* __restrict__ cnt, const float* __restrict__ buf_t,
                         const float* __restrict__ buf_e, const float* __restrict__ acc,
                         float* __restrict__ out) {
    __shared__ float st[CAP];
    __shared__ float vlo, vhi;
    __shared__ float red[16][4];
    const int b = blockIdx.x;
    const int b_lo = sel_i[b * 4 + 0];
    int n = (b_lo < 0) ? 0 : cnt[b];
    if (n > CAP) n = CAP;
    for (int i = threadIdx.x; i < n; i += blockDim.x) st[i] = buf_t[(size_t)b * CAP + i];
    if (threadIdx.x == 0) { vlo = 0.f; vhi = 0.f; }
    __syncthreads();
    const int klo = sel_i[b * 4 + 2];
    const int khi = sel_i[b * 4 + 3];
    for (int i = threadIdx.x; i < n; i += blockDim.x) {
        float x = st[i];
        int r = 0;
        for (int j = 0; j < n; ++j) {
            float y = st[j];
            r += (y < x) || (y == x && j < i);
        }
        if (r == klo) vlo = x;
        if (r == khi) vhi = x;
    }
    __syncthreads();
    const float frac = sel_f[b * 2 + 0];
    const float thresh = (b_lo < 0) ? MASK_TH : (vlo + frac * (vhi - vlo));
    float hs = 0.f, bs = 0.f, hc = 0.f, bc = 0.f;
    for (int i = threadIdx.x; i < n; i += blockDim.x) {
        float t = st[i];
        float e2 = buf_e[(size_t)b * CAP + i];
        if (t > thresh) { hs += e2; hc += 1.f; }
        else            { bs += e2; bc += 1.f; }
    }
    #pragma unroll
    for (int off = 32; off > 0; off >>= 1) {
        hs += __shfl_down(hs, off);
        bs += __shfl_down(bs, off);
        hc += __shfl_down(hc, off);
        bc += __shfl_down(bc, off);
    }
    const int wid = threadIdx.x >> 6;
    const int lane = threadIdx.x & 63;
    if (lane == 0) { red[wid][0] = hs; red[wid][1] = bs; red[wid][2] = hc; red[wid][3] = bc; }
    __syncthreads();
    if (threadIdx.x == 0) {
        float a0 = 0, a1 = 0, a2 = 0, a3 = 0;
        const int nw = blockDim.x >> 6;
        for (int w = 0; w < nw; ++w) { a0 += red[w][0]; a1 += red[w][1]; a2 += red[w][2]; a3 += red[w][3]; }
        float th = acc[b * 4 + 0] + a0;
        float tb = acc[b * 4 + 1] + a1;
        float nh = acc[b * 4 + 2] + a2;
        float nb = acc[b * 4 + 3] + a3;
        float hl = th / (nh + EPSF);
        float bl = tb / (nb + EPSF);
        atomicAdd(out, (5.0f * hl + bl) * (1.0f / (float)BATCH));
    }
}

extern "C" void kernel_launch(void* const* d_in, const int* in_sizes, int n_in,
                              void* d_out, int out_size, void* d_ws, size_t ws_size,
                              hipStream_t stream) {
    const float* pred = (const float*)d_in[0];
    const float* tgt  = (const float*)d_in[1];
    float* out = (float*)d_out;
    const int total = in_sizes[0];
    const int nper = total / BATCH;

    int*   hist  = (int*)d_ws;                      // B*NBINS ints
    int*   cnt   = hist + BATCH * NBINS;            // B ints
    int*   sel_i = cnt + BATCH;                     // B*4 ints
    float* sel_f = (float*)(sel_i + BATCH * 4);     // B*2 floats
    float* acc   = sel_f + BATCH * 2;               // B*4 floats
    float* buf_t = acc + BATCH * 4;                 // B*CAP floats
    float* buf_e = buf_t + BATCH * CAP;             // B*CAP floats

    const size_t zero_bytes = (size_t)((char*)buf_t - (char*)d_ws);
    hipMemsetAsync(d_ws, 0, zero_bytes, stream);

    k_hist  <<<dim3(128, BATCH), 256, 0, stream>>>(tgt, hist, nper);
    k_scan  <<<BATCH, SCAN_T, 0, stream>>>(hist, sel_i, sel_f, out, nper);
    k_fused <<<dim3(128, BATCH), 256, 0, stream>>>(pred, tgt, sel_i, cnt, buf_t, buf_e, acc, nper);
    k_finish<<<BATCH, 1024, 0, stream>>>(sel_i, sel_f, cnt, buf_t, buf_e, acc, out);
}